// Round 9
// baseline (303.277 us; speedup 1.0000x reference)
//
#include <hip/hip_runtime.h>
#include <hip/hip_bf16.h>
#include <cstdint>
#include <cstddef>

typedef __hip_bfloat16 bf16;
typedef __attribute__((ext_vector_type(8))) __bf16 bf16x8;
typedef __attribute__((ext_vector_type(4))) float floatx4;

#define GPTR(p) ((const __attribute__((address_space(1))) void*)(p))
#define LPTR(p) ((__attribute__((address_space(3))) void*)(p))

__device__ __forceinline__ floatx4 mfma16(bf16x8 a, bf16x8 b, floatx4 c) {
  return __builtin_amdgcn_mfma_f32_16x16x32_bf16(a, b, c, 0, 0, 0);
}

// ---------------------------------------------------------------------------
// fp32 -> bf16 bulk convert (x and weights pre-cast once)
// ---------------------------------------------------------------------------
__global__ __launch_bounds__(256) void cvt_bf16(const float* __restrict__ in,
                                                bf16* __restrict__ out, int n4) {
  for (int i = blockIdx.x * 256 + threadIdx.x; i < n4; i += gridDim.x * 256) {
    float4 v = ((const float4*)in)[i];
    alignas(8) bf16 t[4] = {__float2bfloat16(v.x), __float2bfloat16(v.y),
                            __float2bfloat16(v.z), __float2bfloat16(v.w)};
    *(uint64_t*)(out + (size_t)i * 4) = *(const uint64_t*)t;
  }
}

// ---------------------------------------------------------------------------
// Fused QKV projection (round-8, verified): A[8192,1024] @ [Wq;Wk;Wv]^T bf16.
// ---------------------------------------------------------------------------
__global__ __launch_bounds__(256) void gemm_qkv(
    const bf16* __restrict__ A, const bf16* __restrict__ Wq,
    const bf16* __restrict__ Wk, const bf16* __restrict__ Wv,
    bf16* __restrict__ qout, bf16* __restrict__ kout,
    bf16* __restrict__ vTout) {
  __shared__ alignas(16) bf16 As[128 * 32];
  __shared__ alignas(16) bf16 Bs[128 * 32];
  const int tid = threadIdx.x;
  const int lane = tid & 63;
  const int w = tid >> 6;
  const int wr = w >> 1, wc = w & 1;
  const int quad = lane >> 4, c = lane & 15;
  const int m0 = blockIdx.y * 128;
  const int nb = blockIdx.x;

  int mode, nloc;
  const bf16* Wp;
  if (nb < 8) {
    mode = 1; Wp = Wq + (size_t)nb * 128 * 1024; nloc = nb * 128;
  } else if (nb < 10) {
    mode = 2; Wp = Wk + (size_t)(nb - 8) * 128 * 1024; nloc = (nb - 8) * 128;
  } else {
    mode = 3; Wp = Wv + (size_t)(nb - 10) * 128 * 1024; nloc = (nb - 10) * 128;
  }

  const int i0 = tid, i1 = tid + 256;
  const bf16* ga0 = A + (size_t)(m0 + (i0 >> 2)) * 1024 + (i0 & 3) * 8;
  const bf16* ga1 = A + (size_t)(m0 + (i1 >> 2)) * 1024 + (i1 & 3) * 8;
  const bf16* gb0 = Wp + (size_t)(i0 >> 2) * 1024 + (i0 & 3) * 8;
  const bf16* gb1 = Wp + (size_t)(i1 >> 2) * 1024 + (i1 & 3) * 8;

  floatx4 acc[4][4] = {};

  for (int kt = 0; kt < 32; ++kt) {
    if (kt) __syncthreads();
    __builtin_amdgcn_global_load_lds(GPTR(ga0), LPTR(&As[i0 * 8]), 16, 0, 0);
    __builtin_amdgcn_global_load_lds(GPTR(ga1), LPTR(&As[i1 * 8]), 16, 0, 0);
    __builtin_amdgcn_global_load_lds(GPTR(gb0), LPTR(&Bs[i0 * 8]), 16, 0, 0);
    __builtin_amdgcn_global_load_lds(GPTR(gb1), LPTR(&Bs[i1 * 8]), 16, 0, 0);
    ga0 += 32; ga1 += 32; gb0 += 32; gb1 += 32;
    __syncthreads();
    bf16x8 af[4], bfr[4];
#pragma unroll
    for (int i = 0; i < 4; ++i)
      af[i] = *(const bf16x8*)&As[(wr * 64 + i * 16 + c) * 32 + quad * 8];
#pragma unroll
    for (int j = 0; j < 4; ++j)
      bfr[j] = *(const bf16x8*)&Bs[(wc * 64 + j * 16 + c) * 32 + quad * 8];
#pragma unroll
    for (int i = 0; i < 4; ++i)
#pragma unroll
      for (int j = 0; j < 4; ++j)
        acc[i][j] = mfma16(af[i], bfr[j], acc[i][j]);
  }

  if (mode == 3) {
#pragma unroll
    for (int i = 0; i < 4; ++i)
#pragma unroll
      for (int j = 0; j < 4; ++j) {
        int m = m0 + wr * 64 + i * 16 + quad * 4;
        int n = nloc + wc * 64 + j * 16 + c;
        int b = m >> 10, t = m & 1023, g = n >> 6, d = n & 63;
        alignas(8) bf16 tmp[4];
#pragma unroll
        for (int r = 0; r < 4; ++r) tmp[r] = __float2bfloat16(acc[i][j][r]);
        *(uint64_t*)(vTout + (((size_t)(b * 4 + g)) * 64 + d) * 1024 + t) =
            *(const uint64_t*)tmp;
      }
    return;
  }

  const float scale = (mode == 1) ? 0.125f : 1.0f;
#pragma unroll
  for (int i = 0; i < 4; ++i)
#pragma unroll
    for (int j = 0; j < 4; ++j)
#pragma unroll
      for (int r = 0; r < 4; ++r) {
        int m = m0 + wr * 64 + i * 16 + quad * 4 + r;
        int n = nloc + wc * 64 + j * 16 + c;
        int b = m >> 10, t = m & 1023;
        bf16 v = __float2bfloat16(acc[i][j][r] * scale);
        if (mode == 1) {
          int h = n >> 6;
          qout[(((size_t)(b * 16 + h)) * 1024 + t) * 64 + (n & 63)] = v;
        } else {
          int g = n >> 6;
          kout[(((size_t)(b * 4 + g)) * 1024 + t) * 64 + (n & 63)] = v;
        }
      }
}

// ---------------------------------------------------------------------------
// O-projection (round-8, verified): attn @ Wo^T -> fp32 d_out.
// ---------------------------------------------------------------------------
__global__ __launch_bounds__(256) void gemm_o(const bf16* __restrict__ A,
                                              const bf16* __restrict__ W,
                                              float* __restrict__ out) {
  __shared__ alignas(16) bf16 As[128 * 32];
  __shared__ alignas(16) bf16 Bs[128 * 32];
  const int tid = threadIdx.x;
  const int lane = tid & 63;
  const int w = tid >> 6;
  const int wr = w >> 1, wc = w & 1;
  const int quad = lane >> 4, c = lane & 15;
  const int m0 = blockIdx.y * 128, n0 = blockIdx.x * 128;

  const int i0 = tid, i1 = tid + 256;
  const bf16* ga0 = A + (size_t)(m0 + (i0 >> 2)) * 1024 + (i0 & 3) * 8;
  const bf16* ga1 = A + (size_t)(m0 + (i1 >> 2)) * 1024 + (i1 & 3) * 8;
  const bf16* gb0 = W + (size_t)(n0 + (i0 >> 2)) * 1024 + (i0 & 3) * 8;
  const bf16* gb1 = W + (size_t)(n0 + (i1 >> 2)) * 1024 + (i1 & 3) * 8;

  floatx4 acc[4][4] = {};

  for (int kt = 0; kt < 32; ++kt) {
    if (kt) __syncthreads();
    __builtin_amdgcn_global_load_lds(GPTR(ga0), LPTR(&As[i0 * 8]), 16, 0, 0);
    __builtin_amdgcn_global_load_lds(GPTR(ga1), LPTR(&As[i1 * 8]), 16, 0, 0);
    __builtin_amdgcn_global_load_lds(GPTR(gb0), LPTR(&Bs[i0 * 8]), 16, 0, 0);
    __builtin_amdgcn_global_load_lds(GPTR(gb1), LPTR(&Bs[i1 * 8]), 16, 0, 0);
    ga0 += 32; ga1 += 32; gb0 += 32; gb1 += 32;
    __syncthreads();
    bf16x8 af[4], bfr[4];
#pragma unroll
    for (int i = 0; i < 4; ++i)
      af[i] = *(const bf16x8*)&As[(wr * 64 + i * 16 + c) * 32 + quad * 8];
#pragma unroll
    for (int j = 0; j < 4; ++j)
      bfr[j] = *(const bf16x8*)&Bs[(wc * 64 + j * 16 + c) * 32 + quad * 8];
#pragma unroll
    for (int i = 0; i < 4; ++i)
#pragma unroll
      for (int j = 0; j < 4; ++j)
        acc[i][j] = mfma16(af[i], bfr[j], acc[i][j]);
  }

#pragma unroll
  for (int i = 0; i < 4; ++i)
#pragma unroll
    for (int j = 0; j < 4; ++j)
#pragma unroll
      for (int r = 0; r < 4; ++r) {
        int m = m0 + wr * 64 + i * 16 + quad * 4 + r;
        int n = n0 + wc * 64 + j * 16 + c;
        out[(size_t)m * 1024 + n] = acc[i][j][r];
      }
}

// ---------------------------------------------------------------------------
// Staged 64x64 bf16 tile with XOR-8 column-block swizzle (round-7, verified).
// ---------------------------------------------------------------------------
__device__ __forceinline__ void stage_tile_swz(const bf16* __restrict__ g,
                                               int gstride, bf16* __restrict__ dst,
                                               int tid) {
#pragma unroll
  for (int s = 0; s < 2; ++s) {
    int f = s * 256 + tid;
    int r = f >> 3, cb = f & 7;
    int cbg = cb ^ (r & 7);
    __builtin_amdgcn_global_load_lds(GPTR(g + (size_t)r * gstride + cbg * 8),
                                     LPTR(dst + f * 8), 16, 0, 0);
  }
}

__device__ __forceinline__ bf16x8 read_frag_swz(const bf16* __restrict__ tile,
                                                int row, int cb) {
  return *(const bf16x8*)&tile[row * 64 + ((cb ^ (row & 7)) * 8)];
}

// ---------------------------------------------------------------------------
// Flash attention, S^T form, ASYNC-PREFETCH K-loop (round-9 change):
//  - K/V tiles double-buffered; stage(i+1) issued right AFTER the top
//    barrier of iter i, so the next barrier's vmcnt(0) drain hits loads
//    that had a full iteration to land (round-8 staged immediately before
//    the barrier that waited on them: 3 barriers/iter, ~50% stall).
//  - P in its own buffer (no Ks overlay) -> mid-iteration barriers gone.
//    ONE __syncthreads per iter. P write->read is intra-wave (4 lanes of
//    the same q-row): __threadfence_block + wave_barrier, round-7-verified.
// LDS: qEl 33792 + K dbuf 16384 + V dbuf 16384 + P 9216 = 75776 B
//   -> 2 blocks/CU (trade: 12->8 waves/CU for 3x fewer barrier drains).
// ---------------------------------------------------------------------------
__global__ __launch_bounds__(256, 2) void attn_kernel(
    const bf16* __restrict__ q_ws, const bf16* __restrict__ k_ws,
    const bf16* __restrict__ vT, const float* __restrict__ E,
    bf16* __restrict__ out) {
  __shared__ alignas(16) bf16 qEl[64 * 264];  // bias table, rows lane-private
  __shared__ alignas(16) bf16 Kb[2][64 * 64];  // K tile double buffer
  __shared__ alignas(16) bf16 Vb[2][64 * 64];  // V^T tile double buffer
  __shared__ alignas(16) bf16 Pl[64 * 72];     // P rows (stride 72)
  const int tid = threadIdx.x;
  const int lane = tid & 63, w = tid >> 6;
  const int quad = lane >> 4, c = lane & 15;
  const int bh = blockIdx.y;
  const int b = bh >> 4, h = bh & 15, g = h >> 2;
  const int qb = blockIdx.x * 64 + w * 16;

  const bf16* qrow = q_ws + ((size_t)bh * 1024 + qb + c) * 64;
  bf16x8 qf0 = *(const bf16x8*)(qrow + quad * 8);
  bf16x8 qf1 = *(const bf16x8*)(qrow + 32 + quad * 8);

  const bf16* kbase = k_ws + (size_t)(b * 4 + g) * 1024 * 64;
  const bf16* vbase = vT + (size_t)(b * 4 + g) * 64 * 1024;

  // prefetch tile 0 while computing the qE table
  stage_tile_swz(kbase, 64, Kb[0], tid);
  stage_tile_swz(vbase, 1024, Vb[0], tid);

  // qE[qlocal][p] = q.E[p]  (wave's rows w*16..w*16+15; p in [0,254])
  for (int jn = 0; jn < 16; ++jn) {
    int er = jn * 16 + c;
    er = er > 254 ? 254 : er;
    const float* Ep = E + (size_t)er * 64;
    float4 e0 = *(const float4*)(Ep + quad * 8);
    float4 e1 = *(const float4*)(Ep + quad * 8 + 4);
    float4 e2 = *(const float4*)(Ep + 32 + quad * 8);
    float4 e3 = *(const float4*)(Ep + 32 + quad * 8 + 4);
    alignas(16) bf16 t0b[8] = {
        __float2bfloat16(e0.x), __float2bfloat16(e0.y), __float2bfloat16(e0.z),
        __float2bfloat16(e0.w), __float2bfloat16(e1.x), __float2bfloat16(e1.y),
        __float2bfloat16(e1.z), __float2bfloat16(e1.w)};
    alignas(16) bf16 t1b[8] = {
        __float2bfloat16(e2.x), __float2bfloat16(e2.y), __float2bfloat16(e2.z),
        __float2bfloat16(e2.w), __float2bfloat16(e3.x), __float2bfloat16(e3.y),
        __float2bfloat16(e3.z), __float2bfloat16(e3.w)};
    floatx4 a = {};
    a = mfma16(qf0, *(const bf16x8*)t0b, a);
    a = mfma16(qf1, *(const bf16x8*)t1b, a);
#pragma unroll
    for (int r = 0; r < 4; ++r)
      qEl[(w * 16 + quad * 4 + r) * 264 + jn * 16 + c] = __float2bfloat16(a[r]);
  }

  const bf16* rowE = qEl + (size_t)(w * 16 + c) * 264;
  bf16* rowP = Pl + (size_t)(w * 16 + c) * 72;
  float mrow = -1e30f, lrow = 0.f;
  floatx4 o[4] = {};
  float blo = 0.f, bhi = 0.f;

  for (int it = 0; it < 16; ++it) {
    const int t0 = it * 64;
    __syncthreads();  // stage(it) landed; buf[(it+1)&1] free; qEl visible
    if (it < 15) {    // prefetch next tile; lands by next iter's barrier
      stage_tile_swz(kbase + (size_t)(t0 + 64) * 64, 64, Kb[(it + 1) & 1], tid);
      stage_tile_swz(vbase + (t0 + 64), 1024, Vb[(it + 1) & 1], tid);
    }
    const bf16* Ks = Kb[it & 1];
    const bf16* Vs = Vb[it & 1];
    if (it == 0) {
      blo = __bfloat162float(rowE[254]);  // dlt >= +127 (far past)
      bhi = __bfloat162float(rowE[0]);    // dlt <= -127 (far future)
    }
    floatx4 S[4];
#pragma unroll
    for (int j = 0; j < 4; ++j) {
      bf16x8 kf0 = read_frag_swz(Ks, j * 16 + c, quad);
      bf16x8 kf1 = read_frag_swz(Ks, j * 16 + c, quad + 4);
      floatx4 z = {};
      z = mfma16(kf0, qf0, z);
      S[j] = mfma16(kf1, qf1, z);
    }
    const int dlt0 = qb + c - t0;
    if (t0 <= qb - 190) {
#pragma unroll
      for (int j = 0; j < 4; ++j)
#pragma unroll
        for (int r = 0; r < 4; ++r) S[j][r] += blo;
    } else if (t0 >= qb + 142) {
#pragma unroll
      for (int j = 0; j < 4; ++j)
#pragma unroll
        for (int r = 0; r < 4; ++r) S[j][r] += bhi;
    } else {
#pragma unroll
      for (int j = 0; j < 4; ++j)
#pragma unroll
        for (int r = 0; r < 4; ++r) {
          int dlt = dlt0 - j * 16 - quad * 4 - r;
          dlt = dlt > 127 ? 127 : (dlt < -127 ? -127 : dlt);
          S[j][r] += __bfloat162float(rowE[dlt + 127]);
        }
    }
    float mx = -1e30f;
#pragma unroll
    for (int j = 0; j < 4; ++j)
#pragma unroll
      for (int r = 0; r < 4; ++r) mx = fmaxf(mx, S[j][r]);
    mx = fmaxf(mx, __shfl_xor(mx, 16, 64));
    mx = fmaxf(mx, __shfl_xor(mx, 32, 64));
    float nm = fmaxf(mrow, mx);
    float alpha = __expf(mrow - nm);
    float rs = 0.f;
#pragma unroll
    for (int j = 0; j < 4; ++j)
#pragma unroll
      for (int r = 0; r < 4; ++r) {
        float p = __expf(S[j][r] - nm);
        S[j][r] = p;
        rs += p;
      }
    rs += __shfl_xor(rs, 16, 64);
    rs += __shfl_xor(rs, 32, 64);
    lrow = lrow * alpha + rs;
    mrow = nm;
    // P -> own buffer (4 lanes of same q-row write disjoint columns)
#pragma unroll
    for (int j = 0; j < 4; ++j) {
      alignas(8) bf16 tmp[4];
#pragma unroll
      for (int r = 0; r < 4; ++r) tmp[r] = __float2bfloat16(S[j][r]);
      *(uint64_t*)(rowP + j * 16 + quad * 4) = *(const uint64_t*)tmp;
    }
    float av[4];
#pragma unroll
    for (int r = 0; r < 4; ++r) av[r] = __shfl(alpha, quad * 4 + r, 64);
#pragma unroll
    for (int jj = 0; jj < 4; ++jj)
#pragma unroll
      for (int r = 0; r < 4; ++r) o[jj][r] *= av[r];
    __threadfence_block();
    __builtin_amdgcn_wave_barrier();  // intra-wave P write->read ordering
    bf16x8 pf0 = *(const bf16x8*)(rowP + quad * 8);
    bf16x8 pf1 = *(const bf16x8*)(rowP + 32 + quad * 8);
#pragma unroll
    for (int jj = 0; jj < 4; ++jj) {
      bf16x8 vf0 = read_frag_swz(Vs, jj * 16 + c, quad);
      bf16x8 vf1 = read_frag_swz(Vs, jj * 16 + c, quad + 4);
      o[jj] = mfma16(pf0, vf0, o[jj]);
      o[jj] = mfma16(pf1, vf1, o[jj]);
    }
    __builtin_amdgcn_wave_barrier();  // keep P reads before next overwrite
  }

  float lr4[4];
#pragma unroll
  for (int r = 0; r < 4; ++r) lr4[r] = __shfl(lrow, quad * 4 + r, 64);
#pragma unroll
  for (int jj = 0; jj < 4; ++jj)
#pragma unroll
    for (int r = 0; r < 4; ++r) {
      int qi = qb + quad * 4 + r;
      out[(((size_t)b * 1024 + qi) * 16 + h) * 64 + jj * 16 + c] =
          __float2bfloat16(o[jj][r] / lr4[r]);
    }
}

// ---------------------------------------------------------------------------
// Memory plan (ws 24 MB, proven):
//   d_out (32 MB fp32): [0,16M) q bf16 | [16M,32M) x_bf16 (dead before gemm_o).
//   ws: k 4MB @0 | vT 4MB @4M | attn 16MB @8M
//   Wq/Wk/Wv_bf inside attn region (dead before attn_kernel writes it);
//   Wo_bf @0 inside k region (converted after attn_kernel consumed k).
// ---------------------------------------------------------------------------
extern "C" void kernel_launch(void* const* d_in, const int* in_sizes, int n_in,
                              void* d_out, int out_size, void* d_ws,
                              size_t ws_size, hipStream_t stream) {
  const float* x = (const float*)d_in[0];
  const float* Wq = (const float*)d_in[1];
  const float* Wk = (const float*)d_in[2];
  const float* Wv = (const float*)d_in[3];
  const float* Wo = (const float*)d_in[4];
  const float* E = (const float*)d_in[5];

  char* ws = (char*)d_ws;
  bf16* q_ws = (bf16*)d_out;                           // [0,16M) of d_out
  bf16* x_bf = (bf16*)((char*)d_out + (16ull << 20));  // [16M,32M) of d_out
  bf16* k_ws = (bf16*)(ws);
  bf16* vT = (bf16*)(ws + (4ull << 20));
  bf16* attn = (bf16*)(ws + (8ull << 20));
  bf16* Wq_bf = (bf16*)(ws + (8ull << 20));            // 2 MB   (attn region)
  bf16* Wk_bf = (bf16*)(ws + (10ull << 20));           // 0.5 MB (attn region)
  bf16* Wv_bf = (bf16*)(ws + (10ull << 20) + (512ull << 10));  // 0.5 MB
  bf16* Wo_bf = (bf16*)(ws);                           // 2 MB   (k region)
  float* outp = (float*)d_out;

  cvt_bf16<<<2048, 256, 0, stream>>>(x, x_bf, 2097152);
  cvt_bf16<<<1024, 256, 0, stream>>>(Wq, Wq_bf, 262144);
  cvt_bf16<<<256, 256, 0, stream>>>(Wk, Wk_bf, 65536);
  cvt_bf16<<<256, 256, 0, stream>>>(Wv, Wv_bf, 65536);
  gemm_qkv<<<dim3(12, 64), 256, 0, stream>>>(x_bf, Wq_bf, Wk_bf, Wv_bf,
                                             q_ws, k_ws, vT);
  attn_kernel<<<dim3(16, 128), 256, 0, stream>>>(q_ws, k_ws, vT, E, attn);
  cvt_bf16<<<1024, 256, 0, stream>>>(Wo, Wo_bf, 262144);
  gemm_o<<<dim3(8, 64), 256, 0, stream>>>(attn, Wo_bf, outp);
}